// Round 16
// baseline (408.891 us; speedup 1.0000x reference)
//
#include <hip/hip_runtime.h>
#include <cstdint>

#define N_NODES   100000
#define N_EDGES   3200000
#define EMB       64
#define NUM_GRAPHS 512
#define NB        391        // dst-buckets of 256 nodes
#define CAP       9216       // bucket capacity (mean 8184, 11-sigma headroom)
#define PCHUNK    4096
#define PBLOCKS   ((N_EDGES + PCHUNK - 1) / PCHUNK)   // 782
#define CVTBLKS   ((N_NODES * 32 + 255) / 256)        // 12500

__device__ __forceinline__ float bflo(unsigned u) { return __uint_as_float(u << 16); }
__device__ __forceinline__ float bfhi(unsigned u) { return __uint_as_float(u & 0xFFFF0000u); }
__device__ __forceinline__ unsigned rne_bf16(float f) {
    unsigned b = __float_as_uint(f);
    return (b + 0x7FFFu + ((b >> 16) & 1u)) >> 16;
}

// ===================== build: partition (blocks < PBLOCKS) ∥ cvt-to-slice-major (rest) =====================
// xs layout: [slice][node][8 uints] -- slice s holds channels 16s..16s+15 (32B/node/slice).
__global__ void build_kernel(const int* __restrict__ ei, int* __restrict__ bcnt,
                             unsigned* __restrict__ gpairs,
                             const float* __restrict__ x, unsigned* __restrict__ xs) {
    __shared__ unsigned sp[PCHUNK];        // 16 KB
    __shared__ unsigned short sb[PCHUNK];  // 8 KB
    __shared__ int scnt[512];
    __shared__ int soff[512];
    __shared__ int scur[512];
    __shared__ int gbase[512];
    __shared__ int s[256];
    int t = threadIdx.x;

    if (blockIdx.x >= PBLOCKS) {           // ---- cvt part ----
        int i = (blockIdx.x - PBLOCKS) * 256 + t;   // over N_NODES*32 channel-pairs
        if (i < N_NODES * 32) {
            int n = i >> 5, k = i & 31;             // channels 2k, 2k+1
            float2 f = ((const float2*)x)[i];
            unsigned u = rne_bf16(f.x) | (rne_bf16(f.y) << 16);
            int slice = k >> 3, uu = k & 7;
            xs[((size_t)slice * N_NODES + n) * 8 + uu] = u;
        }
        return;
    }

    // ---- partition part (validated r13 body) ----
    for (int i = t; i < 512; i += 256) scnt[i] = 0;
    __syncthreads();
    int base = blockIdx.x * PCHUNK;
    int lim  = min(N_EDGES - base, PCHUNK);
    for (int k = t; k < lim; k += 256) {
        int d = ei[N_EDGES + base + k];
        atomicAdd(&scnt[d >> 8], 1);
    }
    __syncthreads();
    int a0 = scnt[2 * t], a1 = scnt[2 * t + 1];
    int p = a0 + a1;
    s[t] = p; __syncthreads();
    for (int d = 1; d < 256; d <<= 1) {
        int add = (t >= d) ? s[t - d] : 0;
        __syncthreads();
        s[t] += add;
        __syncthreads();
    }
    int excl = s[t] - p;
    soff[2 * t] = excl;       soff[2 * t + 1] = excl + a0;
    scur[2 * t] = excl;       scur[2 * t + 1] = excl + a0;
    __syncthreads();
    for (int i = t; i < NB; i += 256) gbase[i] = i * CAP + atomicAdd(&bcnt[i], scnt[i]);
    __syncthreads();
    for (int k = t; k < lim; k += 256) {
        int sId = ei[base + k];
        int d   = ei[N_EDGES + base + k];
        int b   = d >> 8;
        int pos = atomicAdd(&scur[b], 1);
        sp[pos] = (unsigned)sId | ((unsigned)(d & 255) << 17);   // src:17b, local dst:8b
        sb[pos] = (unsigned short)b;
    }
    __syncthreads();
    for (int i = t; i < lim; i += 256) {
        int b = sb[i];
        gpairs[gbase[b] + (i - soff[b])] = sp[i];
    }
}

// fallback build (no cvt blocks)
__global__ void build_kernel_f32(const int* __restrict__ ei, int* __restrict__ bcnt,
                                 unsigned* __restrict__ gpairs) {
    __shared__ unsigned sp[PCHUNK];
    __shared__ unsigned short sb[PCHUNK];
    __shared__ int scnt[512];
    __shared__ int soff[512];
    __shared__ int scur[512];
    __shared__ int gbase[512];
    __shared__ int s[256];
    int t = threadIdx.x;
    for (int i = t; i < 512; i += 256) scnt[i] = 0;
    __syncthreads();
    int base = blockIdx.x * PCHUNK;
    int lim  = min(N_EDGES - base, PCHUNK);
    for (int k = t; k < lim; k += 256) {
        int d = ei[N_EDGES + base + k];
        atomicAdd(&scnt[d >> 8], 1);
    }
    __syncthreads();
    int a0 = scnt[2 * t], a1 = scnt[2 * t + 1];
    int p = a0 + a1;
    s[t] = p; __syncthreads();
    for (int d = 1; d < 256; d <<= 1) {
        int add = (t >= d) ? s[t - d] : 0;
        __syncthreads();
        s[t] += add;
        __syncthreads();
    }
    int excl = s[t] - p;
    soff[2 * t] = excl;       soff[2 * t + 1] = excl + a0;
    scur[2 * t] = excl;       scur[2 * t + 1] = excl + a0;
    __syncthreads();
    for (int i = t; i < NB; i += 256) gbase[i] = i * CAP + atomicAdd(&bcnt[i], scnt[i]);
    __syncthreads();
    for (int k = t; k < lim; k += 256) {
        int sId = ei[base + k];
        int d   = ei[N_EDGES + base + k];
        int b   = d >> 8;
        int pos = atomicAdd(&scur[b], 1);
        sp[pos] = (unsigned)sId | ((unsigned)(d & 255) << 17);
        sb[pos] = (unsigned short)b;
    }
    __syncthreads();
    for (int i = t; i < lim; i += 256) {
        int b = sb[i];
        gpairs[gbase[b] + (i - soff[b])] = sp[i];
    }
}

// ---------------- per-bucket (r14 body): inline bucket scan + counts + indeg/rowstart/dinv + scatter ----------------
__global__ void bscatter2_kernel(const unsigned* __restrict__ gpairs, const int* __restrict__ bcnt,
                                 int* __restrict__ ebuf,
                                 int* __restrict__ indeg, int* __restrict__ rowstart,
                                 float* __restrict__ dinv) {
    int b = blockIdx.x, t = threadIdx.x, nlo = b << 8;
    __shared__ int pref[512];
    __shared__ int lcnt[256];
    __shared__ int lcur[256];
    __shared__ int s[256];

    int c0 = (2 * t < NB) ? bcnt[2 * t] : 0;
    int c1 = (2 * t + 1 < NB) ? bcnt[2 * t + 1] : 0;
    int pp = c0 + c1;
    s[t] = pp; __syncthreads();
    for (int d = 1; d < 256; d <<= 1) {
        int add = (t >= d) ? s[t - d] : 0;
        __syncthreads();
        s[t] += add;
        __syncthreads();
    }
    int excl2 = s[t] - pp;
    pref[2 * t] = excl2;
    pref[2 * t + 1] = excl2 + c0;
    lcnt[t] = 0;
    __syncthreads();
    int base = pref[b];

    int cnt = bcnt[b];
    const unsigned* gp = gpairs + (size_t)b * CAP;
    for (int i = t; i < cnt; i += 256) atomicAdd(&lcnt[(gp[i] >> 17) & 255], 1);
    __syncthreads();
    int v = lcnt[t];
    s[t] = v; __syncthreads();
    for (int d = 1; d < 256; d <<= 1) {
        int add = (t >= d) ? s[t - d] : 0;
        __syncthreads();
        s[t] += add;
        __syncthreads();
    }
    int excl = s[t] - v;
    int n = nlo + t;
    if (n < N_NODES) {
        indeg[n] = v;
        rowstart[n] = base + excl;
        dinv[n] = rsqrtf((float)(v + 1));
    }
    lcur[t] = base + excl;
    __syncthreads();
    for (int i = t; i < cnt; i += 256) {
        unsigned pk = gp[i];
        int pos = atomicAdd(&lcur[(pk >> 17) & 255], 1);
        ebuf[pos] = (int)(pk & 0x1FFFFu);
    }
}

// ===================== 4-slice XCD-local gather + diffuse: wave per (node, slice) =====================
// slice = blockIdx&3; under round-robin dispatch XCD j serves slice j%4 -> per-XCD x working set
// = 3.2 MB (L2-fit). lane l: q=l&1 (uint4 = 8 channels), e=l>>1 (32 edge slots/wave-iter).
__global__ void gather4_bf16(const int* __restrict__ ebuf, const int* __restrict__ rowstart,
                             const int* __restrict__ indeg, const float* __restrict__ dinv,
                             const unsigned* __restrict__ xs, const float* __restrict__ x,
                             float* __restrict__ dx) {
    int slice = blockIdx.x & 3;
    int node  = (blockIdx.x >> 2) * 4 + (threadIdx.x >> 6);
    if (node >= N_NODES) return;
    int l = threadIdx.x & 63;
    int q = l & 1;
    int e = l >> 1;
    int start = rowstart[node];
    int cnt   = indeg[node];
    float dn  = dinv[node];
    const uint4* __restrict__ xs4 = ((const uint4*)xs) + (size_t)slice * N_NODES * 2;

    float a0 = 0.f, a1 = 0.f, a2 = 0.f, a3 = 0.f, a4 = 0.f, a5 = 0.f, a6 = 0.f, a7 = 0.f;
    int j = 0;
    for (; j + 32 <= cnt; j += 32) {       // 32 edges per wave-iter, 16B/lane
        int sA = ebuf[start + j + e];
        float wA = dinv[sA] * dn;
        uint4 v = xs4[sA * 2 + q];
        a0 += bflo(v.x) * wA; a1 += bfhi(v.x) * wA;
        a2 += bflo(v.y) * wA; a3 += bfhi(v.y) * wA;
        a4 += bflo(v.z) * wA; a5 += bfhi(v.z) * wA;
        a6 += bflo(v.w) * wA; a7 += bfhi(v.w) * wA;
    }
    if (e < cnt - j) {
        int sA = ebuf[start + j + e];
        float wA = dinv[sA] * dn;
        uint4 v = xs4[sA * 2 + q];
        a0 += bflo(v.x) * wA; a1 += bfhi(v.x) * wA;
        a2 += bflo(v.y) * wA; a3 += bfhi(v.y) * wA;
        a4 += bflo(v.z) * wA; a5 += bfhi(v.z) * wA;
        a6 += bflo(v.w) * wA; a7 += bfhi(v.w) * wA;
    }
    // reduce across the 32 edge slots (lanes with same q: stride 2)
    a0 += __shfl_xor(a0, 2); a1 += __shfl_xor(a1, 2); a2 += __shfl_xor(a2, 2); a3 += __shfl_xor(a3, 2);
    a4 += __shfl_xor(a4, 2); a5 += __shfl_xor(a5, 2); a6 += __shfl_xor(a6, 2); a7 += __shfl_xor(a7, 2);
    a0 += __shfl_xor(a0, 4); a1 += __shfl_xor(a1, 4); a2 += __shfl_xor(a2, 4); a3 += __shfl_xor(a3, 4);
    a4 += __shfl_xor(a4, 4); a5 += __shfl_xor(a5, 4); a6 += __shfl_xor(a6, 4); a7 += __shfl_xor(a7, 4);
    a0 += __shfl_xor(a0, 8); a1 += __shfl_xor(a1, 8); a2 += __shfl_xor(a2, 8); a3 += __shfl_xor(a3, 8);
    a4 += __shfl_xor(a4, 8); a5 += __shfl_xor(a5, 8); a6 += __shfl_xor(a6, 8); a7 += __shfl_xor(a7, 8);
    a0 += __shfl_xor(a0, 16); a1 += __shfl_xor(a1, 16); a2 += __shfl_xor(a2, 16); a3 += __shfl_xor(a3, 16);
    a4 += __shfl_xor(a4, 16); a5 += __shfl_xor(a5, 16); a6 += __shfl_xor(a6, 16); a7 += __shfl_xor(a7, 16);
    a0 += __shfl_xor(a0, 32); a1 += __shfl_xor(a1, 32); a2 += __shfl_xor(a2, 32); a3 += __shfl_xor(a3, 32);
    a4 += __shfl_xor(a4, 32); a5 += __shfl_xor(a5, 32); a6 += __shfl_xor(a6, 32); a7 += __shfl_xor(a7, 32);

    if (l < 2) {   // lanes 0,1 hold q=0,1 sums: channels slice*16 + l*8 .. +7 (self term fp32)
        const float4* __restrict__ x4f = (const float4*)x;
        float4 xv0 = x4f[node * 16 + slice * 4 + l * 2];
        float4 xv1 = x4f[node * 16 + slice * 4 + l * 2 + 1];
        float s2 = dn * dn;
        float4 w0, w1;
        w0.x = 0.9f * (a0 + xv0.x * s2) + 0.1f * xv0.x;
        w0.y = 0.9f * (a1 + xv0.y * s2) + 0.1f * xv0.y;
        w0.z = 0.9f * (a2 + xv0.z * s2) + 0.1f * xv0.z;
        w0.w = 0.9f * (a3 + xv0.w * s2) + 0.1f * xv0.w;
        w1.x = 0.9f * (a4 + xv1.x * s2) + 0.1f * xv1.x;
        w1.y = 0.9f * (a5 + xv1.y * s2) + 0.1f * xv1.y;
        w1.z = 0.9f * (a6 + xv1.z * s2) + 0.1f * xv1.z;
        w1.w = 0.9f * (a7 + xv1.w * s2) + 0.1f * xv1.w;
        ((float4*)dx)[node * 16 + slice * 4 + l * 2]     = w0;
        ((float4*)dx)[node * 16 + slice * 4 + l * 2 + 1] = w1;
    }
}

// ===================== node MLP (validated r3 form): wave per node =====================
__global__ void node_mlp_kernel(const float* __restrict__ dx,
                                const float* __restrict__ wn1, const float* __restrict__ bn1,
                                const float* __restrict__ wn2, const float* __restrict__ bn2,
                                float* __restrict__ gl) {
    __shared__ float wn1s[EMB * EMB];
    __shared__ float bn1s[EMB];
    __shared__ float wn2s[EMB];
    for (int i = threadIdx.x; i < EMB * EMB; i += blockDim.x) wn1s[i] = wn1[i];
    if (threadIdx.x < EMB) { bn1s[threadIdx.x] = bn1[threadIdx.x]; wn2s[threadIdx.x] = wn2[threadIdx.x]; }
    __syncthreads();
    int n = (blockIdx.x * blockDim.x + threadIdx.x) >> 6;
    if (n >= N_NODES) return;
    int j = threadIdx.x & 63;
    float rowv = dx[n * EMB + j];
    float acc = bn1s[j];
#pragma unroll
    for (int c = 0; c < EMB; ++c) {
        float b = __shfl(rowv, c);
        acc += b * wn1s[c * EMB + j];
    }
    float h = fmaxf(acc, 0.0f);
    float t = h * wn2s[j];
#pragma unroll
    for (int off = 32; off; off >>= 1) t += __shfl_xor(t, off);
    if (j == 0) gl[n] = t + bn2[0];
}

// ===================== fp32 fused gather (round-9 body; ws fallback tier) =====================
__global__ void gather_mlp_kernel(const int* __restrict__ ebuf, const int* __restrict__ rowstart,
                                  const int* __restrict__ indeg, const float* __restrict__ dinv,
                                  const float* __restrict__ x, float* __restrict__ dx,
                                  const float* __restrict__ wn1, const float* __restrict__ bn1,
                                  const float* __restrict__ wn2, const float* __restrict__ bn2,
                                  float* __restrict__ gl) {
    __shared__ float wn1s[EMB * EMB];
    __shared__ float bn1s[EMB];
    __shared__ float wn2s[EMB];
    for (int i = threadIdx.x; i < EMB * EMB; i += blockDim.x) wn1s[i] = wn1[i];
    if (threadIdx.x < EMB) { bn1s[threadIdx.x] = bn1[threadIdx.x]; wn2s[threadIdx.x] = wn2[threadIdx.x]; }
    __syncthreads();

    int wid = (blockIdx.x * blockDim.x + threadIdx.x) >> 6;
    if (wid >= N_NODES) return;
    int n = __builtin_amdgcn_readfirstlane(wid);
    int l = threadIdx.x & 63;
    int g = l >> 4;
    int q = l & 15;
    int start = rowstart[n];
    int cnt   = indeg[n];
    float dn  = dinv[n];
    const float4* __restrict__ x4 = (const float4*)x;

    float ax = 0.f, ay = 0.f, az = 0.f, aw = 0.f;
    int j = 0;
    for (; j + 8 <= cnt; j += 8) {
        int sA = ebuf[start + j + g];
        int sB = ebuf[start + j + 4 + g];
        float wA = dinv[sA] * dn;
        float wB = dinv[sB] * dn;
        float4 vA = x4[sA * 16 + q];
        float4 vB = x4[sB * 16 + q];
        ax += vA.x * wA + vB.x * wB;
        ay += vA.y * wA + vB.y * wB;
        az += vA.z * wA + vB.z * wB;
        aw += vA.w * wA + vB.w * wB;
    }
    if (j + 4 <= cnt) {
        int sA = ebuf[start + j + g];
        float wA = dinv[sA] * dn;
        float4 vA = x4[sA * 16 + q];
        ax += vA.x * wA; ay += vA.y * wA; az += vA.z * wA; aw += vA.w * wA;
        j += 4;
    }
    int rem = cnt - j;
    if (g < rem) {
        int sA = ebuf[start + j + g];
        float wA = dinv[sA] * dn;
        float4 vA = x4[sA * 16 + q];
        ax += vA.x * wA; ay += vA.y * wA; az += vA.z * wA; aw += vA.w * wA;
    }
    ax += __shfl_xor(ax, 16); ax += __shfl_xor(ax, 32);
    ay += __shfl_xor(ay, 16); ay += __shfl_xor(ay, 32);
    az += __shfl_xor(az, 16); az += __shfl_xor(az, 32);
    aw += __shfl_xor(aw, 16); aw += __shfl_xor(aw, 32);

    float4 xv = x4[n * 16 + q];
    float s2 = dn * dn;
    float r0 = 0.9f * (ax + xv.x * s2) + 0.1f * xv.x;
    float r1 = 0.9f * (ay + xv.y * s2) + 0.1f * xv.y;
    float r2 = 0.9f * (az + xv.z * s2) + 0.1f * xv.z;
    float r3 = 0.9f * (aw + xv.w * s2) + 0.1f * xv.w;
    if (l < 16) {
        float4 rv; rv.x = r0; rv.y = r1; rv.z = r2; rv.w = r3;
        ((float4*)dx)[n * 16 + q] = rv;
    }
    float rr[4] = {r0, r1, r2, r3};
    float am = bn1s[l];
#pragma unroll
    for (int c = 0; c < EMB; ++c) {
        float b = __shfl(rr[c & 3], c >> 2);
        am += b * wn1s[c * EMB + l];
    }
    float h = fmaxf(am, 0.0f);
    float t = h * wn2s[l];
#pragma unroll
    for (int off = 32; off; off >>= 1) t += __shfl_xor(t, off);
    if (l == 0) gl[n] = t + bn2[0];
}

// ===================== pooling+graphMLP (blocks 0..511) ∥ expsum (blocks 512..767) =====================
__device__ inline int lower_bound_i(const int* a, int n, int key) {
    int lo = 0, hi = n;
    while (lo < hi) {
        int mid = (lo + hi) >> 1;
        if (a[mid] < key) lo = mid + 1; else hi = mid;
    }
    return lo;
}
__global__ void poolexp_kernel(const float* __restrict__ dx, const int* __restrict__ batch,
                               const float* __restrict__ wc1, const float* __restrict__ bc1,
                               const float* __restrict__ wc2, const float* __restrict__ bc2,
                               float* __restrict__ alphag,
                               const float* __restrict__ gl, float* __restrict__ gsum) {
    __shared__ float red[4][EMB];
    __shared__ float p[EMB];
    __shared__ float h[EMB];
    __shared__ float red1[256];

    if (blockIdx.x >= NUM_GRAPHS) {        // ---- expsum part ----
        int vb = blockIdx.x - NUM_GRAPHS;  // 0..255
        float s = 0.0f;
        for (int i = vb * 256 + threadIdx.x; i < N_NODES; i += 256 * 256)
            s += expf(gl[i]);
        red1[threadIdx.x] = s; __syncthreads();
        for (int t = 128; t; t >>= 1) {
            if ((int)threadIdx.x < t) red1[threadIdx.x] += red1[threadIdx.x + t];
            __syncthreads();
        }
        if (threadIdx.x == 0) atomicAdd(gsum, red1[0]);
        return;
    }

    // ---- pool + graph MLP part ----
    int g = blockIdx.x;
    int lo = lower_bound_i(batch, N_NODES, g);
    int hi = lower_bound_i(batch, N_NODES, g + 1);
    int lane = threadIdx.x & 63;
    int w = threadIdx.x >> 6;
    float acc = 0.0f;
    for (int n = lo + w; n < hi; n += 4) acc += dx[n * EMB + lane];
    red[w][lane] = acc; __syncthreads();
    if (threadIdx.x < EMB) {
        float s = red[0][threadIdx.x] + red[1][threadIdx.x] + red[2][threadIdx.x] + red[3][threadIdx.x];
        int cnt = hi - lo;
        p[threadIdx.x] = cnt > 0 ? s / (float)cnt : 0.0f;
    }
    __syncthreads();
    if (threadIdx.x < EMB) {
        int j = threadIdx.x;
        float a = bc1[j];
        for (int c = 0; c < EMB; ++c) a += p[c] * wc1[c * EMB + j];
        h[j] = fmaxf(a, 0.0f);
    }
    __syncthreads();
    if (threadIdx.x < 128) {
        int o = threadIdx.x;
        float a = bc2[o];
        for (int j = 0; j < EMB; ++j) a += h[j] * wc2[j * 256 + o];
        alphag[g * 128 + o] = tanhf(a);
    }
}

// ===================== final =====================
__global__ void final_kernel(const float* __restrict__ x, const int* __restrict__ batch,
                             const float* __restrict__ gl, const float* __restrict__ gsum,
                             const float* __restrict__ alphag, float* __restrict__ out) {
    int n = (blockIdx.x * blockDim.x + threadIdx.x) >> 6;
    if (n >= N_NODES) return;
    int lane = threadIdx.x & 63;
    int g = batch[n];
    float gamma = expf(gl[n]) / gsum[0];
    float a0 = alphag[g * 128 + lane];
    float a1 = alphag[g * 128 + 64 + lane];
    float t = gamma * (x[n * EMB + lane] + 1.0f);
    out[n * EMB + lane] = fmaxf(a0 * t, a1 * t);
}

extern "C" void kernel_launch(void* const* d_in, const int* in_sizes, int n_in,
                              void* d_out, int out_size, void* d_ws, size_t ws_size,
                              hipStream_t stream) {
    const float* x     = (const float*)d_in[0];
    const int*   ei    = (const int*)d_in[1];
    const int*   batch = (const int*)d_in[3];
    const float* wn1 = (const float*)d_in[4];
    const float* bn1 = (const float*)d_in[5];
    const float* wn2 = (const float*)d_in[6];
    const float* bn2 = (const float*)d_in[7];
    const float* wc1 = (const float*)d_in[8];
    const float* bc1 = (const float*)d_in[9];
    const float* wc2 = (const float*)d_in[10];
    const float* bc2 = (const float*)d_in[11];
    float* out = (float*)d_out;

    char* wsb = (char*)d_ws;
    float* dx     = (float*)wsb;                        // 25.6 MB (gpairs aliases: NB*CAP u32 = 14.4 MB)
    float* gl     = dx + (size_t)N_NODES * EMB;
    float* dinv   = gl + N_NODES;
    float* pooled = dinv + N_NODES;                     // 32,768 (unused; layout stability)
    float* alphag = pooled + NUM_GRAPHS * EMB;          // 65,536
    int*   bcnt   = (int*)(alphag + NUM_GRAPHS * 128);  // 512
    float* gsum   = (float*)(bcnt + 512);               // 1 (contiguous with bcnt for memset)
    int*   bbase  = (int*)(gsum + 1);                   // 512 (unused; layout stability)
    int*   indeg  = bbase + 512;                        // 100,000
    int*   rowstart = indeg + N_NODES;                  // 100,000
    int*   ebuf   = rowstart + N_NODES;                 // 3,200,000
    unsigned* xs  = (unsigned*)(ebuf + N_EDGES);        // 3,200,000 u32 (slice-major bf16)
    unsigned* gpairs = (unsigned*)dx;                   // aliases dx (dead after bscatter2)

    size_t need_bf16 = (size_t)((char*)(xs + (size_t)N_NODES * EMB / 2) - wsb);
    int use_bf16 = (ws_size >= need_bf16);

    hipMemsetAsync(bcnt, 0, 513 * sizeof(int), stream);   // bcnt + gsum
    if (use_bf16)
        build_kernel<<<PBLOCKS + CVTBLKS, 256, 0, stream>>>(ei, bcnt, gpairs, x, xs);
    else
        build_kernel_f32<<<PBLOCKS, 256, 0, stream>>>(ei, bcnt, gpairs);
    bscatter2_kernel<<<NB, 256, 0, stream>>>(gpairs, bcnt, ebuf, indeg, rowstart, dinv);
    if (use_bf16) {
        gather4_bf16<<<((N_NODES + 3) / 4) * 4, 256, 0, stream>>>(ebuf, rowstart, indeg, dinv, xs, x, dx);
        node_mlp_kernel<<<(N_NODES * 64) / 256, 256, 0, stream>>>(dx, wn1, bn1, wn2, bn2, gl);
    } else {
        gather_mlp_kernel<<<(N_NODES * 64) / 256, 256, 0, stream>>>(ebuf, rowstart, indeg, dinv, x, dx,
                                                                    wn1, bn1, wn2, bn2, gl);
    }
    poolexp_kernel<<<NUM_GRAPHS + 256, 256, 0, stream>>>(dx, batch, wc1, bc1, wc2, bc2, alphag, gl, gsum);
    final_kernel<<<N_NODES / 4, 256, 0, stream>>>(x, batch, gl, gsum, alphag, out);
}

// Round 17
// 286.232 us; speedup vs baseline: 1.4285x; 1.4285x over previous
//
#include <hip/hip_runtime.h>
#include <cstdint>

#define N_NODES   100000
#define N_EDGES   3200000
#define EMB       64
#define NUM_GRAPHS 512
#define NB        391        // dst-buckets of 256 nodes
#define CAP       9216       // bucket capacity (mean 8184, 11-sigma headroom)
#define PCHUNK    4096
#define PBLOCKS   ((N_EDGES + PCHUNK - 1) / PCHUNK)   // 782
#define CVTBLKS   ((N_NODES * EMB / 2 + 255) / 256)   // 12500

__device__ __forceinline__ float bflo(unsigned u) { return __uint_as_float(u << 16); }
__device__ __forceinline__ float bfhi(unsigned u) { return __uint_as_float(u & 0xFFFF0000u); }
__device__ __forceinline__ unsigned rne_bf16(float f) {
    unsigned b = __float_as_uint(f);
    return (b + 0x7FFFu + ((b >> 16) & 1u)) >> 16;
}

// ===================== build: partition (blocks < PBLOCKS) ∥ cvt (rest) =====================
__global__ void build_kernel(const int* __restrict__ ei, int* __restrict__ bcnt,
                             unsigned* __restrict__ gpairs,
                             const float* __restrict__ x, unsigned* __restrict__ xh) {
    __shared__ unsigned sp[PCHUNK];        // 16 KB
    __shared__ unsigned short sb[PCHUNK];  // 8 KB
    __shared__ int scnt[512];
    __shared__ int soff[512];
    __shared__ int scur[512];
    __shared__ int gbase[512];
    __shared__ int s[256];
    int t = threadIdx.x;

    if (blockIdx.x >= PBLOCKS) {           // ---- cvt part ----
        int i = (blockIdx.x - PBLOCKS) * 256 + t;
        if (i < N_NODES * EMB / 2) {
            float2 f = ((const float2*)x)[i];
            xh[i] = rne_bf16(f.x) | (rne_bf16(f.y) << 16);
        }
        return;
    }

    // ---- partition part (validated r13 body) ----
    for (int i = t; i < 512; i += 256) scnt[i] = 0;
    __syncthreads();
    int base = blockIdx.x * PCHUNK;
    int lim  = min(N_EDGES - base, PCHUNK);
    for (int k = t; k < lim; k += 256) {
        int d = ei[N_EDGES + base + k];
        atomicAdd(&scnt[d >> 8], 1);
    }
    __syncthreads();
    int a0 = scnt[2 * t], a1 = scnt[2 * t + 1];
    int p = a0 + a1;
    s[t] = p; __syncthreads();
    for (int d = 1; d < 256; d <<= 1) {
        int add = (t >= d) ? s[t - d] : 0;
        __syncthreads();
        s[t] += add;
        __syncthreads();
    }
    int excl = s[t] - p;
    soff[2 * t] = excl;       soff[2 * t + 1] = excl + a0;
    scur[2 * t] = excl;       scur[2 * t + 1] = excl + a0;
    __syncthreads();
    for (int i = t; i < NB; i += 256) gbase[i] = i * CAP + atomicAdd(&bcnt[i], scnt[i]);
    __syncthreads();
    for (int k = t; k < lim; k += 256) {
        int sId = ei[base + k];
        int d   = ei[N_EDGES + base + k];
        int b   = d >> 8;
        int pos = atomicAdd(&scur[b], 1);
        sp[pos] = (unsigned)sId | ((unsigned)(d & 255) << 17);   // src:17b, local dst:8b
        sb[pos] = (unsigned short)b;
    }
    __syncthreads();
    for (int i = t; i < lim; i += 256) {
        int b = sb[i];
        gpairs[gbase[b] + (i - soff[b])] = sp[i];
    }
}

// fallback build (no cvt blocks)
__global__ void build_kernel_f32(const int* __restrict__ ei, int* __restrict__ bcnt,
                                 unsigned* __restrict__ gpairs) {
    __shared__ unsigned sp[PCHUNK];
    __shared__ unsigned short sb[PCHUNK];
    __shared__ int scnt[512];
    __shared__ int soff[512];
    __shared__ int scur[512];
    __shared__ int gbase[512];
    __shared__ int s[256];
    int t = threadIdx.x;
    for (int i = t; i < 512; i += 256) scnt[i] = 0;
    __syncthreads();
    int base = blockIdx.x * PCHUNK;
    int lim  = min(N_EDGES - base, PCHUNK);
    for (int k = t; k < lim; k += 256) {
        int d = ei[N_EDGES + base + k];
        atomicAdd(&scnt[d >> 8], 1);
    }
    __syncthreads();
    int a0 = scnt[2 * t], a1 = scnt[2 * t + 1];
    int p = a0 + a1;
    s[t] = p; __syncthreads();
    for (int d = 1; d < 256; d <<= 1) {
        int add = (t >= d) ? s[t - d] : 0;
        __syncthreads();
        s[t] += add;
        __syncthreads();
    }
    int excl = s[t] - p;
    soff[2 * t] = excl;       soff[2 * t + 1] = excl + a0;
    scur[2 * t] = excl;       scur[2 * t + 1] = excl + a0;
    __syncthreads();
    for (int i = t; i < NB; i += 256) gbase[i] = i * CAP + atomicAdd(&bcnt[i], scnt[i]);
    __syncthreads();
    for (int k = t; k < lim; k += 256) {
        int sId = ei[base + k];
        int d   = ei[N_EDGES + base + k];
        int b   = d >> 8;
        int pos = atomicAdd(&scur[b], 1);
        sp[pos] = (unsigned)sId | ((unsigned)(d & 255) << 17);
        sb[pos] = (unsigned short)b;
    }
    __syncthreads();
    for (int i = t; i < lim; i += 256) {
        int b = sb[i];
        gpairs[gbase[b] + (i - soff[b])] = sp[i];
    }
}

// ---------------- per-bucket: inline bucket scan + counts + indeg/rowstart/dinv + scatter ----------------
__global__ void bscatter2_kernel(const unsigned* __restrict__ gpairs, const int* __restrict__ bcnt,
                                 int* __restrict__ ebuf,
                                 int* __restrict__ indeg, int* __restrict__ rowstart,
                                 float* __restrict__ dinv) {
    int b = blockIdx.x, t = threadIdx.x, nlo = b << 8;
    __shared__ int pref[512];
    __shared__ int lcnt[256];
    __shared__ int lcur[256];
    __shared__ int s[256];

    // inline exclusive scan of the 391 bucket counts -> base for this block
    int c0 = (2 * t < NB) ? bcnt[2 * t] : 0;
    int c1 = (2 * t + 1 < NB) ? bcnt[2 * t + 1] : 0;
    int pp = c0 + c1;
    s[t] = pp; __syncthreads();
    for (int d = 1; d < 256; d <<= 1) {
        int add = (t >= d) ? s[t - d] : 0;
        __syncthreads();
        s[t] += add;
        __syncthreads();
    }
    int excl2 = s[t] - pp;
    pref[2 * t] = excl2;
    pref[2 * t + 1] = excl2 + c0;
    lcnt[t] = 0;
    __syncthreads();
    int base = pref[b];

    int cnt = bcnt[b];
    const unsigned* gp = gpairs + (size_t)b * CAP;
    for (int i = t; i < cnt; i += 256) atomicAdd(&lcnt[(gp[i] >> 17) & 255], 1);
    __syncthreads();
    int v = lcnt[t];
    s[t] = v; __syncthreads();
    for (int d = 1; d < 256; d <<= 1) {
        int add = (t >= d) ? s[t - d] : 0;
        __syncthreads();
        s[t] += add;
        __syncthreads();
    }
    int excl = s[t] - v;
    int n = nlo + t;
    if (n < N_NODES) {
        indeg[n] = v;
        rowstart[n] = base + excl;
        dinv[n] = rsqrtf((float)(v + 1));
    }
    lcur[t] = base + excl;
    __syncthreads();
    for (int i = t; i < cnt; i += 256) {
        unsigned pk = gp[i];
        int pos = atomicAdd(&lcur[(pk >> 17) & 255], 1);
        ebuf[pos] = (int)(pk & 0x1FFFFu);
    }
}

// ===================== gather(bf16 rows, 32-deep) + diffuse + node-MLP (r13 body, best measured) =====================
__global__ void gather_mlp_bf16(const int* __restrict__ ebuf, const int* __restrict__ rowstart,
                                const int* __restrict__ indeg, const float* __restrict__ dinv,
                                const float* __restrict__ x, const unsigned* __restrict__ xh,
                                float* __restrict__ dx,
                                const float* __restrict__ wn1, const float* __restrict__ bn1,
                                const float* __restrict__ wn2, const float* __restrict__ bn2,
                                float* __restrict__ gl) {
    __shared__ float wn1s[EMB * EMB];
    __shared__ float bn1s[EMB];
    __shared__ float wn2s[EMB];
    for (int i = threadIdx.x; i < EMB * EMB; i += blockDim.x) wn1s[i] = wn1[i];
    if (threadIdx.x < EMB) { bn1s[threadIdx.x] = bn1[threadIdx.x]; wn2s[threadIdx.x] = wn2[threadIdx.x]; }
    __syncthreads();

    int wid = (blockIdx.x * blockDim.x + threadIdx.x) >> 6;
    if (wid >= N_NODES) return;
    int n = __builtin_amdgcn_readfirstlane(wid);
    int l = threadIdx.x & 63;
    int g = l >> 3;
    int q = l & 7;
    int start = rowstart[n];
    int cnt   = indeg[n];
    float dn  = dinv[n];
    const uint4* __restrict__ xr = (const uint4*)xh;

    float a0 = 0.f, a1 = 0.f, a2 = 0.f, a3 = 0.f, a4 = 0.f, a5 = 0.f, a6 = 0.f, a7 = 0.f;
    int j = 0;
    for (; j + 32 <= cnt; j += 32) {          // 32 rows in flight per wave
        int sA = ebuf[start + j + g];
        int sB = ebuf[start + j + 8 + g];
        int sC = ebuf[start + j + 16 + g];
        int sD = ebuf[start + j + 24 + g];
        float wA = dinv[sA] * dn;
        float wB = dinv[sB] * dn;
        float wC = dinv[sC] * dn;
        float wD = dinv[sD] * dn;
        uint4 vA = xr[sA * 8 + q];
        uint4 vB = xr[sB * 8 + q];
        uint4 vC = xr[sC * 8 + q];
        uint4 vD = xr[sD * 8 + q];
        a0 += bflo(vA.x) * wA + bflo(vB.x) * wB + bflo(vC.x) * wC + bflo(vD.x) * wD;
        a1 += bfhi(vA.x) * wA + bfhi(vB.x) * wB + bfhi(vC.x) * wC + bfhi(vD.x) * wD;
        a2 += bflo(vA.y) * wA + bflo(vB.y) * wB + bflo(vC.y) * wC + bflo(vD.y) * wD;
        a3 += bfhi(vA.y) * wA + bfhi(vB.y) * wB + bfhi(vC.y) * wC + bfhi(vD.y) * wD;
        a4 += bflo(vA.z) * wA + bflo(vB.z) * wB + bflo(vC.z) * wC + bflo(vD.z) * wD;
        a5 += bfhi(vA.z) * wA + bfhi(vB.z) * wB + bfhi(vC.z) * wC + bfhi(vD.z) * wD;
        a6 += bflo(vA.w) * wA + bflo(vB.w) * wB + bflo(vC.w) * wC + bflo(vD.w) * wD;
        a7 += bfhi(vA.w) * wA + bfhi(vB.w) * wB + bfhi(vC.w) * wC + bfhi(vD.w) * wD;
    }
    if (j + 16 <= cnt) {
        int sA = ebuf[start + j + g];
        int sB = ebuf[start + j + 8 + g];
        float wA = dinv[sA] * dn;
        float wB = dinv[sB] * dn;
        uint4 vA = xr[sA * 8 + q];
        uint4 vB = xr[sB * 8 + q];
        a0 += bflo(vA.x) * wA + bflo(vB.x) * wB;
        a1 += bfhi(vA.x) * wA + bfhi(vB.x) * wB;
        a2 += bflo(vA.y) * wA + bflo(vB.y) * wB;
        a3 += bfhi(vA.y) * wA + bfhi(vB.y) * wB;
        a4 += bflo(vA.z) * wA + bflo(vB.z) * wB;
        a5 += bfhi(vA.z) * wA + bfhi(vB.z) * wB;
        a6 += bflo(vA.w) * wA + bflo(vB.w) * wB;
        a7 += bfhi(vA.w) * wA + bfhi(vB.w) * wB;
        j += 16;
    }
    if (j + 8 <= cnt) {
        int sA = ebuf[start + j + g];
        float wA = dinv[sA] * dn;
        uint4 vA = xr[sA * 8 + q];
        a0 += bflo(vA.x) * wA; a1 += bfhi(vA.x) * wA;
        a2 += bflo(vA.y) * wA; a3 += bfhi(vA.y) * wA;
        a4 += bflo(vA.z) * wA; a5 += bfhi(vA.z) * wA;
        a6 += bflo(vA.w) * wA; a7 += bfhi(vA.w) * wA;
        j += 8;
    }
    if (g < cnt - j) {
        int sA = ebuf[start + j + g];
        float wA = dinv[sA] * dn;
        uint4 vA = xr[sA * 8 + q];
        a0 += bflo(vA.x) * wA; a1 += bfhi(vA.x) * wA;
        a2 += bflo(vA.y) * wA; a3 += bfhi(vA.y) * wA;
        a4 += bflo(vA.z) * wA; a5 += bfhi(vA.z) * wA;
        a6 += bflo(vA.w) * wA; a7 += bfhi(vA.w) * wA;
    }
    a0 += __shfl_xor(a0, 8); a0 += __shfl_xor(a0, 16); a0 += __shfl_xor(a0, 32);
    a1 += __shfl_xor(a1, 8); a1 += __shfl_xor(a1, 16); a1 += __shfl_xor(a1, 32);
    a2 += __shfl_xor(a2, 8); a2 += __shfl_xor(a2, 16); a2 += __shfl_xor(a2, 32);
    a3 += __shfl_xor(a3, 8); a3 += __shfl_xor(a3, 16); a3 += __shfl_xor(a3, 32);
    a4 += __shfl_xor(a4, 8); a4 += __shfl_xor(a4, 16); a4 += __shfl_xor(a4, 32);
    a5 += __shfl_xor(a5, 8); a5 += __shfl_xor(a5, 16); a5 += __shfl_xor(a5, 32);
    a6 += __shfl_xor(a6, 8); a6 += __shfl_xor(a6, 16); a6 += __shfl_xor(a6, 32);
    a7 += __shfl_xor(a7, 8); a7 += __shfl_xor(a7, 16); a7 += __shfl_xor(a7, 32);

    const float4* __restrict__ x4 = (const float4*)x;
    float4 xv0 = x4[n * 16 + 2 * q];
    float4 xv1 = x4[n * 16 + 2 * q + 1];
    float s2 = dn * dn;
    float r0 = 0.9f * (a0 + xv0.x * s2) + 0.1f * xv0.x;
    float r1 = 0.9f * (a1 + xv0.y * s2) + 0.1f * xv0.y;
    float r2 = 0.9f * (a2 + xv0.z * s2) + 0.1f * xv0.z;
    float r3 = 0.9f * (a3 + xv0.w * s2) + 0.1f * xv0.w;
    float r4 = 0.9f * (a4 + xv1.x * s2) + 0.1f * xv1.x;
    float r5 = 0.9f * (a5 + xv1.y * s2) + 0.1f * xv1.y;
    float r6 = 0.9f * (a6 + xv1.z * s2) + 0.1f * xv1.z;
    float r7 = 0.9f * (a7 + xv1.w * s2) + 0.1f * xv1.w;
    if (l < 8) {
        float4 w0; w0.x = r0; w0.y = r1; w0.z = r2; w0.w = r3;
        float4 w1; w1.x = r4; w1.y = r5; w1.z = r6; w1.w = r7;
        ((float4*)dx)[n * 16 + 2 * l]     = w0;
        ((float4*)dx)[n * 16 + 2 * l + 1] = w1;
    }

    float rr[8] = {r0, r1, r2, r3, r4, r5, r6, r7};
    float am = bn1s[l];
#pragma unroll
    for (int c = 0; c < EMB; ++c) {
        float b = __shfl(rr[c & 7], c >> 3);
        am += b * wn1s[c * EMB + l];
    }
    float h = fmaxf(am, 0.0f);
    float t = h * wn2s[l];
#pragma unroll
    for (int off = 32; off; off >>= 1) t += __shfl_xor(t, off);
    if (l == 0) gl[n] = t + bn2[0];
}

// ===================== fp32 fused gather (round-9 body; ws fallback tier) =====================
__global__ void gather_mlp_kernel(const int* __restrict__ ebuf, const int* __restrict__ rowstart,
                                  const int* __restrict__ indeg, const float* __restrict__ dinv,
                                  const float* __restrict__ x, float* __restrict__ dx,
                                  const float* __restrict__ wn1, const float* __restrict__ bn1,
                                  const float* __restrict__ wn2, const float* __restrict__ bn2,
                                  float* __restrict__ gl) {
    __shared__ float wn1s[EMB * EMB];
    __shared__ float bn1s[EMB];
    __shared__ float wn2s[EMB];
    for (int i = threadIdx.x; i < EMB * EMB; i += blockDim.x) wn1s[i] = wn1[i];
    if (threadIdx.x < EMB) { bn1s[threadIdx.x] = bn1[threadIdx.x]; wn2s[threadIdx.x] = wn2[threadIdx.x]; }
    __syncthreads();

    int wid = (blockIdx.x * blockDim.x + threadIdx.x) >> 6;
    if (wid >= N_NODES) return;
    int n = __builtin_amdgcn_readfirstlane(wid);
    int l = threadIdx.x & 63;
    int g = l >> 4;
    int q = l & 15;
    int start = rowstart[n];
    int cnt   = indeg[n];
    float dn  = dinv[n];
    const float4* __restrict__ x4 = (const float4*)x;

    float ax = 0.f, ay = 0.f, az = 0.f, aw = 0.f;
    int j = 0;
    for (; j + 8 <= cnt; j += 8) {
        int sA = ebuf[start + j + g];
        int sB = ebuf[start + j + 4 + g];
        float wA = dinv[sA] * dn;
        float wB = dinv[sB] * dn;
        float4 vA = x4[sA * 16 + q];
        float4 vB = x4[sB * 16 + q];
        ax += vA.x * wA + vB.x * wB;
        ay += vA.y * wA + vB.y * wB;
        az += vA.z * wA + vB.z * wB;
        aw += vA.w * wA + vB.w * wB;
    }
    if (j + 4 <= cnt) {
        int sA = ebuf[start + j + g];
        float wA = dinv[sA] * dn;
        float4 vA = x4[sA * 16 + q];
        ax += vA.x * wA; ay += vA.y * wA; az += vA.z * wA; aw += vA.w * wA;
        j += 4;
    }
    int rem = cnt - j;
    if (g < rem) {
        int sA = ebuf[start + j + g];
        float wA = dinv[sA] * dn;
        float4 vA = x4[sA * 16 + q];
        ax += vA.x * wA; ay += vA.y * wA; az += vA.z * wA; aw += vA.w * wA;
    }
    ax += __shfl_xor(ax, 16); ax += __shfl_xor(ax, 32);
    ay += __shfl_xor(ay, 16); ay += __shfl_xor(ay, 32);
    az += __shfl_xor(az, 16); az += __shfl_xor(az, 32);
    aw += __shfl_xor(aw, 16); aw += __shfl_xor(aw, 32);

    float4 xv = x4[n * 16 + q];
    float s2 = dn * dn;
    float r0 = 0.9f * (ax + xv.x * s2) + 0.1f * xv.x;
    float r1 = 0.9f * (ay + xv.y * s2) + 0.1f * xv.y;
    float r2 = 0.9f * (az + xv.z * s2) + 0.1f * xv.z;
    float r3 = 0.9f * (aw + xv.w * s2) + 0.1f * xv.w;
    if (l < 16) {
        float4 rv; rv.x = r0; rv.y = r1; rv.z = r2; rv.w = r3;
        ((float4*)dx)[n * 16 + q] = rv;
    }
    float rr[4] = {r0, r1, r2, r3};
    float am = bn1s[l];
#pragma unroll
    for (int c = 0; c < EMB; ++c) {
        float b = __shfl(rr[c & 3], c >> 2);
        am += b * wn1s[c * EMB + l];
    }
    float h = fmaxf(am, 0.0f);
    float t = h * wn2s[l];
#pragma unroll
    for (int off = 32; off; off >>= 1) t += __shfl_xor(t, off);
    if (l == 0) gl[n] = t + bn2[0];
}

// ===================== pooling+graphMLP (blocks 0..511) ∥ expsum (blocks 512..767) =====================
__device__ inline int lower_bound_i(const int* a, int n, int key) {
    int lo = 0, hi = n;
    while (lo < hi) {
        int mid = (lo + hi) >> 1;
        if (a[mid] < key) lo = mid + 1; else hi = mid;
    }
    return lo;
}
__global__ void poolexp_kernel(const float* __restrict__ dx, const int* __restrict__ batch,
                               const float* __restrict__ wc1, const float* __restrict__ bc1,
                               const float* __restrict__ wc2, const float* __restrict__ bc2,
                               float* __restrict__ alphag,
                               const float* __restrict__ gl, float* __restrict__ gsum) {
    __shared__ float red[4][EMB];
    __shared__ float p[EMB];
    __shared__ float h[EMB];
    __shared__ float red1[256];

    if (blockIdx.x >= NUM_GRAPHS) {        // ---- expsum part ----
        int vb = blockIdx.x - NUM_GRAPHS;  // 0..255
        float s = 0.0f;
        for (int i = vb * 256 + threadIdx.x; i < N_NODES; i += 256 * 256)
            s += expf(gl[i]);
        red1[threadIdx.x] = s; __syncthreads();
        for (int t = 128; t; t >>= 1) {
            if ((int)threadIdx.x < t) red1[threadIdx.x] += red1[threadIdx.x + t];
            __syncthreads();
        }
        if (threadIdx.x == 0) atomicAdd(gsum, red1[0]);
        return;
    }

    // ---- pool + graph MLP part ----
    int g = blockIdx.x;
    int lo = lower_bound_i(batch, N_NODES, g);
    int hi = lower_bound_i(batch, N_NODES, g + 1);
    int lane = threadIdx.x & 63;
    int w = threadIdx.x >> 6;
    float acc = 0.0f;
    for (int n = lo + w; n < hi; n += 4) acc += dx[n * EMB + lane];
    red[w][lane] = acc; __syncthreads();
    if (threadIdx.x < EMB) {
        float s = red[0][threadIdx.x] + red[1][threadIdx.x] + red[2][threadIdx.x] + red[3][threadIdx.x];
        int cnt = hi - lo;
        p[threadIdx.x] = cnt > 0 ? s / (float)cnt : 0.0f;
    }
    __syncthreads();
    if (threadIdx.x < EMB) {
        int j = threadIdx.x;
        float a = bc1[j];
        for (int c = 0; c < EMB; ++c) a += p[c] * wc1[c * EMB + j];
        h[j] = fmaxf(a, 0.0f);
    }
    __syncthreads();
    if (threadIdx.x < 128) {
        int o = threadIdx.x;
        float a = bc2[o];
        for (int j = 0; j < EMB; ++j) a += h[j] * wc2[j * 256 + o];
        alphag[g * 128 + o] = tanhf(a);
    }
}

// ===================== final =====================
__global__ void final_kernel(const float* __restrict__ x, const int* __restrict__ batch,
                             const float* __restrict__ gl, const float* __restrict__ gsum,
                             const float* __restrict__ alphag, float* __restrict__ out) {
    int n = (blockIdx.x * blockDim.x + threadIdx.x) >> 6;
    if (n >= N_NODES) return;
    int lane = threadIdx.x & 63;
    int g = batch[n];
    float gamma = expf(gl[n]) / gsum[0];
    float a0 = alphag[g * 128 + lane];
    float a1 = alphag[g * 128 + 64 + lane];
    float t = gamma * (x[n * EMB + lane] + 1.0f);
    out[n * EMB + lane] = fmaxf(a0 * t, a1 * t);
}

extern "C" void kernel_launch(void* const* d_in, const int* in_sizes, int n_in,
                              void* d_out, int out_size, void* d_ws, size_t ws_size,
                              hipStream_t stream) {
    const float* x     = (const float*)d_in[0];
    const int*   ei    = (const int*)d_in[1];
    const int*   batch = (const int*)d_in[3];
    const float* wn1 = (const float*)d_in[4];
    const float* bn1 = (const float*)d_in[5];
    const float* wn2 = (const float*)d_in[6];
    const float* bn2 = (const float*)d_in[7];
    const float* wc1 = (const float*)d_in[8];
    const float* bc1 = (const float*)d_in[9];
    const float* wc2 = (const float*)d_in[10];
    const float* bc2 = (const float*)d_in[11];
    float* out = (float*)d_out;

    char* wsb = (char*)d_ws;
    float* dx     = (float*)wsb;                        // 25.6 MB (gpairs aliases: NB*CAP u32 = 14.4 MB)
    float* gl     = dx + (size_t)N_NODES * EMB;
    float* dinv   = gl + N_NODES;
    float* pooled = dinv + N_NODES;                     // 32,768 (unused; layout stability)
    float* alphag = pooled + NUM_GRAPHS * EMB;          // 65,536
    int*   bcnt   = (int*)(alphag + NUM_GRAPHS * 128);  // 512
    float* gsum   = (float*)(bcnt + 512);               // 1 (contiguous with bcnt for memset)
    int*   bbase  = (int*)(gsum + 1);                   // 512 (unused; layout stability)
    int*   indeg  = bbase + 512;                        // 100,000
    int*   rowstart = indeg + N_NODES;                  // 100,000
    int*   ebuf   = rowstart + N_NODES;                 // 3,200,000
    unsigned* xh  = (unsigned*)(ebuf + N_EDGES);        // 3,200,000 u32 (bf16 tier)
    unsigned* gpairs = (unsigned*)dx;                   // aliases dx (dead after bscatter2)

    size_t need_bf16 = (size_t)((char*)(xh + (size_t)N_NODES * EMB / 2) - wsb);
    int use_bf16 = (ws_size >= need_bf16);

    hipMemsetAsync(bcnt, 0, 513 * sizeof(int), stream);   // bcnt + gsum
    if (use_bf16)
        build_kernel<<<PBLOCKS + CVTBLKS, 256, 0, stream>>>(ei, bcnt, gpairs, x, xh);
    else
        build_kernel_f32<<<PBLOCKS, 256, 0, stream>>>(ei, bcnt, gpairs);
    bscatter2_kernel<<<NB, 256, 0, stream>>>(gpairs, bcnt, ebuf, indeg, rowstart, dinv);
    if (use_bf16)
        gather_mlp_bf16<<<(N_NODES * 64) / 256, 256, 0, stream>>>(ebuf, rowstart, indeg, dinv, x, xh, dx,
                                                                  wn1, bn1, wn2, bn2, gl);
    else
        gather_mlp_kernel<<<(N_NODES * 64) / 256, 256, 0, stream>>>(ebuf, rowstart, indeg, dinv, x, dx,
                                                                    wn1, bn1, wn2, bn2, gl);
    poolexp_kernel<<<NUM_GRAPHS + 256, 256, 0, stream>>>(dx, batch, wc1, bc1, wc2, bc2, alphag, gl, gsum);
    final_kernel<<<N_NODES / 4, 256, 0, stream>>>(x, batch, gl, gsum, alphag, out);
}